// Round 8
// baseline (113.228 us; speedup 1.0000x reference)
//
#include <hip/hip_runtime.h>
#include <hip/hip_bf16.h>

// Problem constants
#define NG   8
#define ND   16
#define NL   1024
#define NB   16
#define NE   8
#define NOUT 64
#define NKS  3
#define NK   4
#define NLP  1022   // L - KS + 1

// Output layout (flat concat of reference return tuple)
#define OUT_LOSS  (NB*NG*NOUT*NLP)   // 8372224
#define OUT_GATES (OUT_LOSS + 1)     // 8372225

typedef short bf16x8 __attribute__((ext_vector_type(8)));  // 8 bf16 (4 VGPR)
typedef float f32x4  __attribute__((ext_vector_type(4)));  // MFMA acc

#define MFMA16(A, B, C) __builtin_amdgcn_mfma_f32_16x16x32_bf16((A), (B), (C), 0, 0, 0)

// tanh via exp2: tanh(x) = 1 - 2/(1+2^(2*log2(e)*x)). Correct +-inf limits.
__device__ __forceinline__ float tanh_fast(float x) {
    float e = exp2f(x * 2.885390081777927f);   // 2*log2(e)
    return 1.0f - 2.0f / (e + 1.0f);
}

// --- split-bf16 helpers ---
__device__ __forceinline__ unsigned fbits(float a) { return __builtin_bit_cast(unsigned, a); }
__device__ __forceinline__ float resid(float a) {   // a - bf16_trunc(a), exact
    return a - __builtin_bit_cast(float, fbits(a) & 0xFFFF0000u);
}
// truncation pack (prep-side, unchanged from verified rounds 6/7)
__device__ __forceinline__ int pack2(float a, float b) {
    return (int)((fbits(a) >> 16) | (fbits(b) & 0xFFFF0000u));
}
// RNE bf16 via HW cvt; resid vs RNE-hi is exact in fp32 (Sterbenz zone)
__device__ __forceinline__ unsigned short bfb(float v) {
    __hip_bfloat16 h = __float2bfloat16(v);
    return __builtin_bit_cast(unsigned short, h);
}
__device__ __forceinline__ float bff(unsigned short s) {
    return __builtin_bit_cast(float, ((unsigned)s) << 16);
}

// Gating math for one (g,b): softmax(80x8 matvec) -> top4 -> renorm.
__device__ __forceinline__ void compute_gates_f(
    const float* __restrict__ x, const float* __restrict__ wg,
    int g, int b, float gates[8])
{
    float gi[80];
    const float* xrow = x + (size_t)(b * 128 + g * 16) * 1024 + (1024 - 6);
    #pragma unroll
    for (int d = 0; d < 16; ++d) {
        #pragma unroll
        for (int tt = 0; tt < 5; ++tt) gi[d * 5 + tt] = xrow[d * 1024 + tt];
    }
    float lg[8];
    #pragma unroll
    for (int e = 0; e < 8; ++e) lg[e] = 0.f;
    const float* wgg = wg + g * 640;
    #pragma unroll
    for (int j = 0; j < 80; ++j) {
        const float v = gi[j];
        #pragma unroll
        for (int e = 0; e < 8; ++e) lg[e] = fmaf(v, wgg[j * 8 + e], lg[e]);
    }
    float mx = lg[0];
    #pragma unroll
    for (int e = 1; e < 8; ++e) mx = fmaxf(mx, lg[e]);
    float s = 0.f;
    #pragma unroll
    for (int e = 0; e < 8; ++e) { lg[e] = expf(lg[e] - mx); s += lg[e]; }
    const float invsm = 1.f / s;
    #pragma unroll
    for (int e = 0; e < 8; ++e) lg[e] *= invsm;

    int used = 0;
    float tv[4]; int ti[4];
    #pragma unroll
    for (int k = 0; k < 4; ++k) {
        float bv = -1.f; int be = 0;
        #pragma unroll
        for (int e = 0; e < 8; ++e) {
            if (!((used >> e) & 1) && lg[e] > bv) { bv = lg[e]; be = e; }
        }
        tv[k] = bv; ti[k] = be; used |= (1 << be);
    }
    const float s4 = tv[0] + tv[1] + tv[2] + tv[3];
    const float invs = 1.f / (s4 + 1e-6f);
    #pragma unroll
    for (int e = 0; e < 8; ++e) {
        float v = 0.f;
        #pragma unroll
        for (int k = 0; k < 4; ++k) if (ti[k] == e) v = tv[k] * invs;
        gates[e] = v;
    }
}

// ---------------------------------------------------------------------------
// Prep kernel, 137 blocks x 256 threads (unchanged from round 7 - verified):
//   blocks 0..127  : weffA[gb] split-bf16 A-frags, beff[gb]
//   blocks 128..135: w1fA[g] split-bf16 A-frags (k = tap*16 + i, pad to 64)
//   block 136      : gates_out + load-balancing loss
// Fragment convention: unit(s,mt,ks): lane slot = lgrp*16 + row, elem e <->
// k = ks*32 + lgrp*8 + e.
// ---------------------------------------------------------------------------
__global__ __launch_bounds__(256) void prep_kernel(
    const float* __restrict__ x,   const float* __restrict__ wg,
    const float* __restrict__ c1w, const float* __restrict__ c2w,
    const float* __restrict__ c2b,
    float* __restrict__ out, int4* __restrict__ weffA,
    float* __restrict__ beff, int4* __restrict__ w1fA)
{
    const int bid = blockIdx.x;
    const int t   = threadIdx.x;

    __shared__ float glds[128][8];
    __shared__ float impa[64], loda[64];
    __shared__ float lossg[8];

    if (bid < 128) {
        const int gb = bid, g = gb >> 4, b = gb & 15;
        float gt[8];
        compute_gates_f(x, wg, g, b, gt);   // uniform across block

        const int o  = t >> 2;               // 0..63
        const int iq = (t & 3) * 16;         // 0,16,32,48
        const float* w2g = c2w + (size_t)g * 512 * 64 + (size_t)o * 8 * 64 + iq;
        float acc[16];
        #pragma unroll
        for (int q = 0; q < 16; ++q) acc[q] = 0.f;
        #pragma unroll
        for (int e = 0; e < 8; ++e) {
            const float4* src = (const float4*)(w2g + e * 64);
            #pragma unroll
            for (int q = 0; q < 4; ++q) {
                float4 v = src[q];
                acc[q*4+0] = fmaf(gt[e], v.x, acc[q*4+0]);
                acc[q*4+1] = fmaf(gt[e], v.y, acc[q*4+1]);
                acc[q*4+2] = fmaf(gt[e], v.z, acc[q*4+2]);
                acc[q*4+3] = fmaf(gt[e], v.w, acc[q*4+3]);
            }
        }
        const int mt  = o >> 4;
        const int ks  = iq >> 5;
        const int lgA = (iq & 31) >> 3;      // 0 or 2
        int4* wdst = weffA + gb * 1024 + mt * 128 + ks * 64;
        #pragma unroll
        for (int R = 0; R < 2; ++R) {
            int4 whi, wlo;
            whi.x = pack2(acc[R*8+0], acc[R*8+1]);
            whi.y = pack2(acc[R*8+2], acc[R*8+3]);
            whi.z = pack2(acc[R*8+4], acc[R*8+5]);
            whi.w = pack2(acc[R*8+6], acc[R*8+7]);
            wlo.x = pack2(resid(acc[R*8+0]), resid(acc[R*8+1]));
            wlo.y = pack2(resid(acc[R*8+2]), resid(acc[R*8+3]));
            wlo.z = pack2(resid(acc[R*8+4]), resid(acc[R*8+5]));
            wlo.w = pack2(resid(acc[R*8+6]), resid(acc[R*8+7]));
            const int slot = (lgA + R) * 16 + (o & 15);
            wdst[slot]       = whi;          // s = 0 (hi)
            wdst[512 + slot] = wlo;          // s = 1 (lo)
        }
        if (t < 64) {
            const float* b2g = c2b + g * 512;
            float a = 0.f;
            #pragma unroll
            for (int e = 0; e < 8; ++e) a = fmaf(gt[e], b2g[t * 8 + e], a);
            beff[gb * 64 + t] = a;
        }
    } else if (bid < 136) {
        const int g = bid - 128;
        for (int u = t; u < 1024; u += 256) {
            const int s    = u >> 9;
            const int mt   = (u >> 7) & 3;
            const int ks   = (u >> 6) & 1;
            const int lgrp = (u >> 4) & 3;
            const int m    = u & 15;
            const int o    = mt * 16 + m;
            float v[8];
            #pragma unroll
            for (int e = 0; e < 8; ++e) {
                const int k = ks * 32 + lgrp * 8 + e;     // k = tap*16 + i
                if (k < 48) {
                    const int tap = (k < 32) ? (k >> 4) : 2;
                    const int i   = k & 15;
                    const float w = c1w[((size_t)(g * 64 + o) * 16 + i) * 3 + tap];
                    v[e] = (s == 0) ? w : resid(w);
                } else v[e] = 0.f;
            }
            int4 pk;
            pk.x = pack2(v[0], v[1]); pk.y = pack2(v[2], v[3]);
            pk.z = pack2(v[4], v[5]); pk.w = pack2(v[6], v[7]);
            w1fA[(size_t)g * 1024 + u] = pk;
        }
    } else {
        float gates[8];
        const int g = t >> 4, b = t & 15;
        if (t < 128) {
            compute_gates_f(x, wg, g, b, gates);
            #pragma unroll
            for (int e = 0; e < 8; ++e) {
                glds[t][e] = gates[e];
                out[OUT_GATES + (b * 8 + e) * 8 + g] = gates[e];
            }
        }
        __syncthreads();
        if (t < 64) {
            const int gg = t >> 3, e = t & 7;
            float si = 0.f, sl = 0.f;
            for (int bb = 0; bb < 16; ++bb) {
                const float v = glds[gg * 16 + bb][e];
                si += v;
                sl += (v > 0.f) ? 1.f : 0.f;
            }
            impa[t] = si; loda[t] = sl;
        }
        __syncthreads();
        if (t < 8) {
            float m1 = 0.f, m2 = 0.f;
            #pragma unroll
            for (int e = 0; e < 8; ++e) { m1 += impa[t * 8 + e]; m2 += loda[t * 8 + e]; }
            m1 *= 0.125f; m2 *= 0.125f;
            float v1 = 0.f, v2 = 0.f;
            #pragma unroll
            for (int e = 0; e < 8; ++e) {
                const float d1 = impa[t * 8 + e] - m1, d2 = loda[t * 8 + e] - m2;
                v1 += d1 * d1; v2 += d2 * d2;
            }
            v1 *= (1.f / 7.f); v2 *= (1.f / 7.f);
            lossg[t] = v1 / (m1 * m1 + 1e-10f) + v2 / (m2 * m2 + 1e-10f);
        }
        __syncthreads();
        if (t == 0) {
            float tot = 0.f;
            #pragma unroll
            for (int gg = 0; gg < 8; ++gg) tot += lossg[gg];
            out[OUT_LOSS] = 0.01f * tot;
        }
    }
}

// ---------------------------------------------------------------------------
// Main kernel (restructured round 8): one barrier, tl-outer per-wave pipeline.
// Grid 1024 (XCD-swizzled), 4 waves; wave wv owns col-tiles nt = 2wv+tl.
//
// Stage: x tile pre-SPLIT to bf16 hi/lo planes in LDS:
//   row c (0..129), 80 B stride: [hi i0-7 |lo i0-7 |hi i8-15 |lo i8-15]
//   -> conv1 B-fragments are raw 16B ds_read_b128 (zero pack VALU per frag).
// Per tl: {4 B-loads -> 24 MFMA conv1 -> tanh+split-repack into per-wave 4KB
// hfrag region -> 24 MFMA conv2 -> stores}. All cross-wave traffic is the
// single xtile barrier; hfrag is wave-private (lgkmcnt-ordered).
// Peak VGPR ~80 (was ~110+): xB 16 + acc 16 + w-frags 16, tl-serial.
// ---------------------------------------------------------------------------
__global__ __launch_bounds__(256, 4) void main_kernel(
    const float* __restrict__ x,    const int4* __restrict__ w1fA,
    const float* __restrict__ b1,   const int4* __restrict__ weffA,
    const float* __restrict__ beff, float* __restrict__ out)
{
    __shared__ int4 hfrag[1024];        // 16 KB: 4 waves x 256 int4
    __shared__ char xs[130 * 80 + 16]; // 10.4 KB split-x tile

    const int bid  = blockIdx.x;
    const int xcd  = bid & 7;
    const int jj   = bid >> 3;
    const int gb   = ((jj & 15) << 3) | xcd; // same-gb tiles share an XCD
    const int tile = jj >> 4;                // 0..7
    const int g    = gb >> 4, b = gb & 15;
    const int t    = threadIdx.x;
    const int lane = t & 63;
    const int wv   = t >> 6;
    const int col  = lane & 15;
    const int j4   = lane >> 4;              // 0..3
    const int l0   = tile * 128;
    const int wb   = wv * 256;               // per-wave hfrag base (int4 units)

    // ---- stage x tile, pre-split bf16 hi/lo ----
    {
        const int si  = t >> 4;              // channel 0..15
        const int sc0 = t & 15;
        const float* xr = x + (size_t)(b * 128 + g * 16 + si) * 1024;
        const int boff = (si >> 3) * 32 + (si & 7) * 2;
        #pragma unroll
        for (int kk = 0; kk < 9; ++kk) {
            const int c = sc0 + kk * 16;
            if (c < 130) {
                int gc = l0 + c; if (gc > 1023) gc = 1023;   // tail clamp
                const float v = xr[gc];
                const unsigned short hs = bfb(v);
                const unsigned short ls = bfb(v - bff(hs));
                *(unsigned short*)(xs + c * 80 + boff)      = hs;
                *(unsigned short*)(xs + c * 80 + boff + 16) = ls;
            }
        }
    }
    __syncthreads();

    const int4*  w1base = w1fA + g * 1024 + lane;
    const int4*  wAbase = weffA + gb * 1024 + lane;
    const int    rbase  = j4 << 2;
    float* outg = out + (size_t)((b * 8 + g) * 64) * NLP;

    #pragma unroll
    for (int tl = 0; tl < 2; ++tl) {
        // ---- B-fragments for conv1: raw reads from split planes ----
        const int nloc = (wv * 2 + tl) * 16 + col;
        bf16x8 xBh0, xBl0, xBh1, xBl1;
        {
            const char* p0 = xs + (nloc + (j4 >> 1)) * 80 + (j4 & 1) * 32;
            int4 bh = *(const int4*)p0;
            int4 bl = *(const int4*)(p0 + 16);
            xBh0 = __builtin_bit_cast(bf16x8, bh);
            xBl0 = __builtin_bit_cast(bf16x8, bl);
            const char* p1 = xs + (nloc + 2) * 80 + (j4 & 1) * 32;
            int4 ch_ = *(const int4*)p1;
            int4 cl_ = *(const int4*)(p1 + 16);
            if (j4 >= 2) {                   // k >= 48 zero-padded
                ch_.x = ch_.y = ch_.z = ch_.w = 0;
                cl_.x = cl_.y = cl_.z = cl_.w = 0;
            }
            xBh1 = __builtin_bit_cast(bf16x8, ch_);
            xBl1 = __builtin_bit_cast(bf16x8, cl_);
        }

        // ---- conv1 via MFMA ----
        f32x4 acc1[4];
        #pragma unroll
        for (int mt = 0; mt < 4; ++mt)
            acc1[mt] = *(const f32x4*)(b1 + g * 64 + mt * 16 + rbase);
        #pragma unroll
        for (int mt = 0; mt < 4; ++mt) {
            bf16x8 Ah0 = *(const bf16x8*)(w1base + mt * 128);
            bf16x8 Ah1 = *(const bf16x8*)(w1base + mt * 128 + 64);
            bf16x8 Al0 = *(const bf16x8*)(w1base + 512 + mt * 128);
            bf16x8 Al1 = *(const bf16x8*)(w1base + 512 + mt * 128 + 64);
            f32x4 a = acc1[mt];
            a = MFMA16(Ah0, xBh0, a);
            a = MFMA16(Ah0, xBl0, a);
            a = MFMA16(Al0, xBh0, a);
            a = MFMA16(Ah1, xBh1, a);
            a = MFMA16(Ah1, xBl1, a);
            a = MFMA16(Al1, xBh1, a);
            acc1[mt] = a;
        }

        // ---- tanh + split repack into wave-private hfrag region ----
        {
            char* base = (char*)hfrag;
            const int woff = (j4 & 1) * 8;
            const int lgt0 = j4 >> 1;
            #pragma unroll
            for (int mt = 0; mt < 4; ++mt) {
                const float t0 = tanh_fast(acc1[mt][0]);
                const float t1 = tanh_fast(acc1[mt][1]);
                const float t2 = tanh_fast(acc1[mt][2]);
                const float t3 = tanh_fast(acc1[mt][3]);
                const unsigned short h0 = bfb(t0), h1 = bfb(t1);
                const unsigned short h2 = bfb(t2), h3 = bfb(t3);
                uint2 whi, wlo;
                whi.x = (unsigned)h0 | ((unsigned)h1 << 16);
                whi.y = (unsigned)h2 | ((unsigned)h3 << 16);
                wlo.x = (unsigned)bfb(t0 - bff(h0)) | ((unsigned)bfb(t1 - bff(h1)) << 16);
                wlo.y = (unsigned)bfb(t2 - bff(h2)) | ((unsigned)bfb(t3 - bff(h3)) << 16);
                const int kst = mt >> 1;
                const int lgt = ((mt & 1) << 1) + lgt0;
                const int u   = wb + kst * 64 + lgt * 16 + col;
                *(uint2*)(base + u * 16 + woff)           = whi;   // s=0 (hi)
                *(uint2*)(base + (u + 128) * 16 + woff)   = wlo;   // s=1 (lo)
            }
        }

        // ---- conv2 (gate-folded 64x64) via MFMA, wave-private read-back ----
        f32x4 acc2[4];
        #pragma unroll
        for (int mt = 0; mt < 4; ++mt)
            acc2[mt] = *(const f32x4*)(beff + gb * 64 + mt * 16 + rbase);
        #pragma unroll
        for (int ks = 0; ks < 2; ++ks) {
            bf16x8 Bh = *(const bf16x8*)&hfrag[wb + ks * 64 + lane];
            bf16x8 Bl = *(const bf16x8*)&hfrag[wb + 128 + ks * 64 + lane];
            #pragma unroll
            for (int mt = 0; mt < 4; ++mt) {
                bf16x8 Ah = *(const bf16x8*)(wAbase + mt * 128 + ks * 64);
                bf16x8 Al = *(const bf16x8*)(wAbase + 512 + mt * 128 + ks * 64);
                f32x4 a = acc2[mt];
                a = MFMA16(Ah, Bh, a);
                a = MFMA16(Ah, Bl, a);
                a = MFMA16(Al, Bh, a);
                acc2[mt] = a;
            }
        }

        // ---- epilogue for this tl (overlaps next tl's compute) ----
        const int cg = l0 + nloc;            // = l0 + (2wv+tl)*16 + col
        if (cg < NLP) {
            #pragma unroll
            for (int mt = 0; mt < 4; ++mt) {
                float* orow = outg + (size_t)(mt * 16 + rbase) * NLP + cg;
                orow[0]             = acc2[mt][0];
                orow[(size_t)NLP]   = acc2[mt][1];
                orow[(size_t)NLP*2] = acc2[mt][2];
                orow[(size_t)NLP*3] = acc2[mt][3];
            }
        }
    }
}

// ---------------------------------------------------------------------------
extern "C" void kernel_launch(void* const* d_in, const int* in_sizes, int n_in,
                              void* d_out, int out_size, void* d_ws, size_t ws_size,
                              hipStream_t stream) {
    const float* x   = (const float*)d_in[0];
    const float* wg  = (const float*)d_in[1];
    const float* c1w = (const float*)d_in[2];
    const float* c1b = (const float*)d_in[3];
    const float* c2w = (const float*)d_in[4];
    const float* c2b = (const float*)d_in[5];
    float* out = (float*)d_out;

    char* ws    = (char*)d_ws;
    int4* weffA = (int4*)ws;                     // 128*1024 int4 = 2 MB
    int4* w1fA  = weffA + 131072;                // 8*1024 int4   = 128 KB
    float* beff = (float*)(w1fA + 8192);         // 8192 floats   = 32 KB
    // total ws: ~2.16 MB

    prep_kernel<<<137, 256, 0, stream>>>(x, wg, c1w, c2w, c2b, out, weffA, beff, w1fA);
    main_kernel<<<1024, 256, 0, stream>>>(x, w1fA, c1b, weffA, beff, out);
}

// Round 9
// 109.022 us; speedup vs baseline: 1.0386x; 1.0386x over previous
//
#include <hip/hip_runtime.h>
#include <hip/hip_bf16.h>

// Problem constants
#define NG   8
#define ND   16
#define NL   1024
#define NB   16
#define NE   8
#define NOUT 64
#define NKS  3
#define NK   4
#define NLP  1022   // L - KS + 1

// Output layout (flat concat of reference return tuple)
#define OUT_LOSS  (NB*NG*NOUT*NLP)   // 8372224
#define OUT_GATES (OUT_LOSS + 1)     // 8372225

typedef short bf16x8 __attribute__((ext_vector_type(8)));  // 8 bf16 (4 VGPR)
typedef float f32x4  __attribute__((ext_vector_type(4)));  // MFMA acc

#define MFMA16(A, B, C) __builtin_amdgcn_mfma_f32_16x16x32_bf16((A), (B), (C), 0, 0, 0)

// tanh via exp2: tanh(x) = 1 - 2/(1+2^(2*log2(e)*x)). Correct +-inf limits.
__device__ __forceinline__ float tanh_fast(float x) {
    float e = exp2f(x * 2.885390081777927f);   // 2*log2(e)
    return 1.0f - 2.0f / (e + 1.0f);
}

// --- split-bf16 helpers ---
__device__ __forceinline__ unsigned fbits(float a) { return __builtin_bit_cast(unsigned, a); }
__device__ __forceinline__ float resid(float a) {   // a - bf16_trunc(a), exact
    return a - __builtin_bit_cast(float, fbits(a) & 0xFFFF0000u);
}
// truncation pack (prep-side, verified rounds 6-8)
__device__ __forceinline__ int pack2(float a, float b) {
    return (int)((fbits(a) >> 16) | (fbits(b) & 0xFFFF0000u));
}
// RNE bf16 via HW cvt (verified round 8)
__device__ __forceinline__ unsigned short bfb(float v) {
    __hip_bfloat16 h = __float2bfloat16(v);
    return __builtin_bit_cast(unsigned short, h);
}
__device__ __forceinline__ float bff(unsigned short s) {
    return __builtin_bit_cast(float, ((unsigned)s) << 16);
}

// Gating math for one (g,b): softmax(80x8 matvec) -> top4 -> renorm.
__device__ __forceinline__ void compute_gates_f(
    const float* __restrict__ x, const float* __restrict__ wg,
    int g, int b, float gates[8])
{
    float gi[80];
    const float* xrow = x + (size_t)(b * 128 + g * 16) * 1024 + (1024 - 6);
    #pragma unroll
    for (int d = 0; d < 16; ++d) {
        #pragma unroll
        for (int tt = 0; tt < 5; ++tt) gi[d * 5 + tt] = xrow[d * 1024 + tt];
    }
    float lg[8];
    #pragma unroll
    for (int e = 0; e < 8; ++e) lg[e] = 0.f;
    const float* wgg = wg + g * 640;
    #pragma unroll
    for (int j = 0; j < 80; ++j) {
        const float v = gi[j];
        #pragma unroll
        for (int e = 0; e < 8; ++e) lg[e] = fmaf(v, wgg[j * 8 + e], lg[e]);
    }
    float mx = lg[0];
    #pragma unroll
    for (int e = 1; e < 8; ++e) mx = fmaxf(mx, lg[e]);
    float s = 0.f;
    #pragma unroll
    for (int e = 0; e < 8; ++e) { lg[e] = expf(lg[e] - mx); s += lg[e]; }
    const float invsm = 1.f / s;
    #pragma unroll
    for (int e = 0; e < 8; ++e) lg[e] *= invsm;

    int used = 0;
    float tv[4]; int ti[4];
    #pragma unroll
    for (int k = 0; k < 4; ++k) {
        float bv = -1.f; int be = 0;
        #pragma unroll
        for (int e = 0; e < 8; ++e) {
            if (!((used >> e) & 1) && lg[e] > bv) { bv = lg[e]; be = e; }
        }
        tv[k] = bv; ti[k] = be; used |= (1 << be);
    }
    const float s4 = tv[0] + tv[1] + tv[2] + tv[3];
    const float invs = 1.f / (s4 + 1e-6f);
    #pragma unroll
    for (int e = 0; e < 8; ++e) {
        float v = 0.f;
        #pragma unroll
        for (int k = 0; k < 4; ++k) if (ti[k] == e) v = tv[k] * invs;
        gates[e] = v;
    }
}

// ---------------------------------------------------------------------------
// Prep kernel, 137 blocks x 256 threads (unchanged, verified rounds 7/8):
//   blocks 0..127  : weffA[gb] split-bf16 A-frags, beff[gb]
//   blocks 128..135: w1fA[g] split-bf16 A-frags (k = tap*16 + i, pad to 64)
//   block 136      : gates_out + load-balancing loss
// Fragment convention: unit(s,mt,ks): lane slot = lgrp*16 + row, elem e <->
// k = ks*32 + lgrp*8 + e.
// ---------------------------------------------------------------------------
__global__ __launch_bounds__(256) void prep_kernel(
    const float* __restrict__ x,   const float* __restrict__ wg,
    const float* __restrict__ c1w, const float* __restrict__ c2w,
    const float* __restrict__ c2b,
    float* __restrict__ out, int4* __restrict__ weffA,
    float* __restrict__ beff, int4* __restrict__ w1fA)
{
    const int bid = blockIdx.x;
    const int t   = threadIdx.x;

    __shared__ float glds[128][8];
    __shared__ float impa[64], loda[64];
    __shared__ float lossg[8];

    if (bid < 128) {
        const int gb = bid, g = gb >> 4, b = gb & 15;
        float gt[8];
        compute_gates_f(x, wg, g, b, gt);   // uniform across block

        const int o  = t >> 2;               // 0..63
        const int iq = (t & 3) * 16;         // 0,16,32,48
        const float* w2g = c2w + (size_t)g * 512 * 64 + (size_t)o * 8 * 64 + iq;
        float acc[16];
        #pragma unroll
        for (int q = 0; q < 16; ++q) acc[q] = 0.f;
        #pragma unroll
        for (int e = 0; e < 8; ++e) {
            const float4* src = (const float4*)(w2g + e * 64);
            #pragma unroll
            for (int q = 0; q < 4; ++q) {
                float4 v = src[q];
                acc[q*4+0] = fmaf(gt[e], v.x, acc[q*4+0]);
                acc[q*4+1] = fmaf(gt[e], v.y, acc[q*4+1]);
                acc[q*4+2] = fmaf(gt[e], v.z, acc[q*4+2]);
                acc[q*4+3] = fmaf(gt[e], v.w, acc[q*4+3]);
            }
        }
        const int mt  = o >> 4;
        const int ks  = iq >> 5;
        const int lgA = (iq & 31) >> 3;      // 0 or 2
        int4* wdst = weffA + gb * 1024 + mt * 128 + ks * 64;
        #pragma unroll
        for (int R = 0; R < 2; ++R) {
            int4 whi, wlo;
            whi.x = pack2(acc[R*8+0], acc[R*8+1]);
            whi.y = pack2(acc[R*8+2], acc[R*8+3]);
            whi.z = pack2(acc[R*8+4], acc[R*8+5]);
            whi.w = pack2(acc[R*8+6], acc[R*8+7]);
            wlo.x = pack2(resid(acc[R*8+0]), resid(acc[R*8+1]));
            wlo.y = pack2(resid(acc[R*8+2]), resid(acc[R*8+3]));
            wlo.z = pack2(resid(acc[R*8+4]), resid(acc[R*8+5]));
            wlo.w = pack2(resid(acc[R*8+6]), resid(acc[R*8+7]));
            const int slot = (lgA + R) * 16 + (o & 15);
            wdst[slot]       = whi;          // s = 0 (hi)
            wdst[512 + slot] = wlo;          // s = 1 (lo)
        }
        if (t < 64) {
            const float* b2g = c2b + g * 512;
            float a = 0.f;
            #pragma unroll
            for (int e = 0; e < 8; ++e) a = fmaf(gt[e], b2g[t * 8 + e], a);
            beff[gb * 64 + t] = a;
        }
    } else if (bid < 136) {
        const int g = bid - 128;
        for (int u = t; u < 1024; u += 256) {
            const int s    = u >> 9;
            const int mt   = (u >> 7) & 3;
            const int ks   = (u >> 6) & 1;
            const int lgrp = (u >> 4) & 3;
            const int m    = u & 15;
            const int o    = mt * 16 + m;
            float v[8];
            #pragma unroll
            for (int e = 0; e < 8; ++e) {
                const int k = ks * 32 + lgrp * 8 + e;     // k = tap*16 + i
                if (k < 48) {
                    const int tap = (k < 32) ? (k >> 4) : 2;
                    const int i   = k & 15;
                    const float w = c1w[((size_t)(g * 64 + o) * 16 + i) * 3 + tap];
                    v[e] = (s == 0) ? w : resid(w);
                } else v[e] = 0.f;
            }
            int4 pk;
            pk.x = pack2(v[0], v[1]); pk.y = pack2(v[2], v[3]);
            pk.z = pack2(v[4], v[5]); pk.w = pack2(v[6], v[7]);
            w1fA[(size_t)g * 1024 + u] = pk;
        }
    } else {
        float gates[8];
        const int g = t >> 4, b = t & 15;
        if (t < 128) {
            compute_gates_f(x, wg, g, b, gates);
            #pragma unroll
            for (int e = 0; e < 8; ++e) {
                glds[t][e] = gates[e];
                out[OUT_GATES + (b * 8 + e) * 8 + g] = gates[e];
            }
        }
        __syncthreads();
        if (t < 64) {
            const int gg = t >> 3, e = t & 7;
            float si = 0.f, sl = 0.f;
            for (int bb = 0; bb < 16; ++bb) {
                const float v = glds[gg * 16 + bb][e];
                si += v;
                sl += (v > 0.f) ? 1.f : 0.f;
            }
            impa[t] = si; loda[t] = sl;
        }
        __syncthreads();
        if (t < 8) {
            float m1 = 0.f, m2 = 0.f;
            #pragma unroll
            for (int e = 0; e < 8; ++e) { m1 += impa[t * 8 + e]; m2 += loda[t * 8 + e]; }
            m1 *= 0.125f; m2 *= 0.125f;
            float v1 = 0.f, v2 = 0.f;
            #pragma unroll
            for (int e = 0; e < 8; ++e) {
                const float d1 = impa[t * 8 + e] - m1, d2 = loda[t * 8 + e] - m2;
                v1 += d1 * d1; v2 += d2 * d2;
            }
            v1 *= (1.f / 7.f); v2 *= (1.f / 7.f);
            lossg[t] = v1 / (m1 * m1 + 1e-10f) + v2 / (m2 * m2 + 1e-10f);
        }
        __syncthreads();
        if (t == 0) {
            float tot = 0.f;
            #pragma unroll
            for (int gg = 0; gg < 8; ++gg) tot += lossg[gg];
            out[OUT_LOSS] = 0.01f * tot;
        }
    }
}

// ---------------------------------------------------------------------------
// Main kernel (round 9): round-7 ILP structure + round-8 pre-split staging.
// Grid 1024 (XCD-swizzled), 4 waves; wave wv owns col-tiles nt = 2wv, 2wv+1,
// BOTH kept in flight (two independent latency chains per phase).
//
// LDS 32 KB: hfrag0 (16 KB, tl=0 B-frags) + regionB (16 KB) where the
// pre-split x tile (10.4 KB) lives until the 2nd barrier, after which
// regionB is reused for tl=1 B-frags (wave-private regions, lgkm-ordered).
// A-fragments (w1fA, weffA) loaded ONCE per mt and used for both tl.
// ---------------------------------------------------------------------------
__global__ __launch_bounds__(256, 4) void main_kernel(
    const float* __restrict__ x,    const int4* __restrict__ w1fA,
    const float* __restrict__ b1,   const int4* __restrict__ weffA,
    const float* __restrict__ beff, float* __restrict__ out)
{
    __shared__ int4 hfrag0[1024];        // 16 KB: tl=0, 4 waves x 256 int4
    __shared__ int4 regionB[1024];       // 16 KB: xs stage, then tl=1 frags
    char* xs = (char*)regionB;           // split-x tile: 130 rows x 80 B

    const int bid  = blockIdx.x;
    const int xcd  = bid & 7;
    const int jj   = bid >> 3;
    const int gb   = ((jj & 15) << 3) | xcd; // same-gb tiles share an XCD
    const int tile = jj >> 4;                // 0..7
    const int g    = gb >> 4, b = gb & 15;
    const int t    = threadIdx.x;
    const int lane = t & 63;
    const int wv   = t >> 6;
    const int col  = lane & 15;
    const int j4   = lane >> 4;              // 0..3
    const int l0   = tile * 128;
    const int wb   = wv * 256;               // per-wave frag base (int4 units)

    // ---- prefetch biases (independent of xs; drain under the barrier) ----
    const int rbase = j4 << 2;
    f32x4 b1v[4], befv[4];
    #pragma unroll
    for (int mt = 0; mt < 4; ++mt) {
        b1v[mt]  = *(const f32x4*)(b1 + g * 64 + mt * 16 + rbase);
        befv[mt] = *(const f32x4*)(beff + gb * 64 + mt * 16 + rbase);
    }

    // ---- stage x tile, pre-split bf16 hi/lo (round-8 layout) ----
    {
        const int si  = t >> 4;              // channel 0..15
        const int sc0 = t & 15;
        const float* xr = x + (size_t)(b * 128 + g * 16 + si) * 1024;
        const int boff = (si >> 3) * 32 + (si & 7) * 2;
        #pragma unroll
        for (int kk = 0; kk < 9; ++kk) {
            const int c = sc0 + kk * 16;
            if (c < 130) {
                int gc = l0 + c; if (gc > 1023) gc = 1023;   // tail clamp
                const float v = xr[gc];
                const unsigned short hs = bfb(v);
                const unsigned short ls = bfb(v - bff(hs));
                *(unsigned short*)(xs + c * 80 + boff)      = hs;
                *(unsigned short*)(xs + c * 80 + boff + 16) = ls;
            }
        }
    }
    __syncthreads();

    // ---- B-fragments for conv1, BOTH tl, raw b128 reads ----
    bf16x8 xBh0[2], xBl0[2], xBh1[2], xBl1[2];   // [tl]
    int nloc[2];
    #pragma unroll
    for (int tl = 0; tl < 2; ++tl) {
        nloc[tl] = (wv * 2 + tl) * 16 + col;
        const char* p0 = xs + (nloc[tl] + (j4 >> 1)) * 80 + (j4 & 1) * 32;
        int4 bh = *(const int4*)p0;
        int4 bl = *(const int4*)(p0 + 16);
        xBh0[tl] = __builtin_bit_cast(bf16x8, bh);
        xBl0[tl] = __builtin_bit_cast(bf16x8, bl);
        const char* p1 = xs + (nloc[tl] + 2) * 80 + (j4 & 1) * 32;
        int4 ch_ = *(const int4*)p1;
        int4 cl_ = *(const int4*)(p1 + 16);
        if (j4 >= 2) {                       // k >= 48 zero-padded
            ch_.x = ch_.y = ch_.z = ch_.w = 0;
            cl_.x = cl_.y = cl_.z = cl_.w = 0;
        }
        xBh1[tl] = __builtin_bit_cast(bf16x8, ch_);
        xBl1[tl] = __builtin_bit_cast(bf16x8, cl_);
    }
    __syncthreads();     // xs dead; regionB reusable for tl=1 h-frags

    // ---- conv1 via MFMA, both tl interleaved, A-frags loaded once ----
    const int4* w1base = w1fA + g * 1024 + lane;
    f32x4 acc1[2][4];
    #pragma unroll
    for (int mt = 0; mt < 4; ++mt) { acc1[0][mt] = b1v[mt]; acc1[1][mt] = b1v[mt]; }
    #pragma unroll
    for (int mt = 0; mt < 4; ++mt) {
        bf16x8 Ah0 = *(const bf16x8*)(w1base + mt * 128);
        bf16x8 Ah1 = *(const bf16x8*)(w1base + mt * 128 + 64);
        bf16x8 Al0 = *(const bf16x8*)(w1base + 512 + mt * 128);
        bf16x8 Al1 = *(const bf16x8*)(w1base + 512 + mt * 128 + 64);
        #pragma unroll
        for (int tl = 0; tl < 2; ++tl) {
            f32x4 a = acc1[tl][mt];
            a = MFMA16(Ah0, xBh0[tl], a);
            a = MFMA16(Ah0, xBl0[tl], a);
            a = MFMA16(Al0, xBh0[tl], a);
            a = MFMA16(Ah1, xBh1[tl], a);
            a = MFMA16(Ah1, xBl1[tl], a);
            a = MFMA16(Al1, xBh1[tl], a);
            acc1[tl][mt] = a;
        }
    }

    // ---- tanh + split repack: tl0 -> hfrag0, tl1 -> regionB ----
    {
        const int woff = (j4 & 1) * 8;
        const int lgt0 = j4 >> 1;
        #pragma unroll
        for (int tl = 0; tl < 2; ++tl) {
            char* base = (tl == 0) ? (char*)hfrag0 : (char*)regionB;
            #pragma unroll
            for (int mt = 0; mt < 4; ++mt) {
                const float t0 = tanh_fast(acc1[tl][mt][0]);
                const float t1 = tanh_fast(acc1[tl][mt][1]);
                const float t2 = tanh_fast(acc1[tl][mt][2]);
                const float t3 = tanh_fast(acc1[tl][mt][3]);
                const unsigned short h0 = bfb(t0), h1 = bfb(t1);
                const unsigned short h2 = bfb(t2), h3 = bfb(t3);
                uint2 whi, wlo;
                whi.x = (unsigned)h0 | ((unsigned)h1 << 16);
                whi.y = (unsigned)h2 | ((unsigned)h3 << 16);
                wlo.x = (unsigned)bfb(t0 - bff(h0)) | ((unsigned)bfb(t1 - bff(h1)) << 16);
                wlo.y = (unsigned)bfb(t2 - bff(h2)) | ((unsigned)bfb(t3 - bff(h3)) << 16);
                const int kst = mt >> 1;
                const int lgt = ((mt & 1) << 1) + lgt0;
                const int u   = wb + kst * 64 + lgt * 16 + col;
                *(uint2*)(base + u * 16 + woff)         = whi;   // s=0 (hi)
                *(uint2*)(base + (u + 128) * 16 + woff) = wlo;   // s=1 (lo)
            }
        }
    }

    // ---- conv2 via MFMA, both tl interleaved, A-frags loaded once ----
    const int4* wAbase = weffA + gb * 1024 + lane;
    f32x4 acc2[2][4];
    #pragma unroll
    for (int mt = 0; mt < 4; ++mt) { acc2[0][mt] = befv[mt]; acc2[1][mt] = befv[mt]; }
    #pragma unroll
    for (int ks = 0; ks < 2; ++ks) {
        bf16x8 Bh0t = *(const bf16x8*)&hfrag0[wb + ks * 64 + lane];
        bf16x8 Bl0t = *(const bf16x8*)&hfrag0[wb + 128 + ks * 64 + lane];
        bf16x8 Bh1t = *(const bf16x8*)&regionB[wb + ks * 64 + lane];
        bf16x8 Bl1t = *(const bf16x8*)&regionB[wb + 128 + ks * 64 + lane];
        #pragma unroll
        for (int mt = 0; mt < 4; ++mt) {
            bf16x8 Ah = *(const bf16x8*)(wAbase + mt * 128 + ks * 64);
            bf16x8 Al = *(const bf16x8*)(wAbase + 512 + mt * 128 + ks * 64);
            f32x4 a0 = acc2[0][mt];
            f32x4 a1 = acc2[1][mt];
            a0 = MFMA16(Ah, Bh0t, a0);
            a1 = MFMA16(Ah, Bh1t, a1);
            a0 = MFMA16(Ah, Bl0t, a0);
            a1 = MFMA16(Ah, Bl1t, a1);
            a0 = MFMA16(Al, Bh0t, a0);
            a1 = MFMA16(Al, Bh1t, a1);
            acc2[0][mt] = a0;
            acc2[1][mt] = a1;
        }
    }

    // ---- epilogue ----
    float* outg = out + (size_t)((b * 8 + g) * 64) * NLP;
    #pragma unroll
    for (int tl = 0; tl < 2; ++tl) {
        const int cg = l0 + nloc[tl];
        if (cg < NLP) {
            #pragma unroll
            for (int mt = 0; mt < 4; ++mt) {
                float* orow = outg + (size_t)(mt * 16 + rbase) * NLP + cg;
                orow[0]             = acc2[tl][mt][0];
                orow[(size_t)NLP]   = acc2[tl][mt][1];
                orow[(size_t)NLP*2] = acc2[tl][mt][2];
                orow[(size_t)NLP*3] = acc2[tl][mt][3];
            }
        }
    }
}

// ---------------------------------------------------------------------------
extern "C" void kernel_launch(void* const* d_in, const int* in_sizes, int n_in,
                              void* d_out, int out_size, void* d_ws, size_t ws_size,
                              hipStream_t stream) {
    const float* x   = (const float*)d_in[0];
    const float* wg  = (const float*)d_in[1];
    const float* c1w = (const float*)d_in[2];
    const float* c1b = (const float*)d_in[3];
    const float* c2w = (const float*)d_in[4];
    const float* c2b = (const float*)d_in[5];
    float* out = (float*)d_out;

    char* ws    = (char*)d_ws;
    int4* weffA = (int4*)ws;                     // 128*1024 int4 = 2 MB
    int4* w1fA  = weffA + 131072;                // 8*1024 int4   = 128 KB
    float* beff = (float*)(w1fA + 8192);         // 8192 floats   = 32 KB
    // total ws: ~2.16 MB

    prep_kernel<<<137, 256, 0, stream>>>(x, wg, c1w, c2w, c2b, out, weffA, beff, w1fA);
    main_kernel<<<1024, 256, 0, stream>>>(x, w1fA, c1b, weffA, beff, out);
}